// Round 1
// baseline (246.823 us; speedup 1.0000x reference)
//
#include <hip/hip_runtime.h>

#define IMG_W 1024
#define IMG_H 1024
#define BATCH 32

__global__ __launch_bounds__(256) void conv3x3_kernel(
    const float* __restrict__ X,
    const float* __restrict__ wt,
    float* __restrict__ out)
{
    const int y  = blockIdx.x;          // row 0..1023
    const int b  = blockIdx.y;          // batch 0..31
    const int c0 = threadIdx.x * 4;     // first of 4 output cols

    const float* img = X + (size_t)b * IMG_H * IMG_W;
    float* orow = out + ((size_t)b * IMG_H + y) * IMG_W + c0;

    const float w0 = wt[0], w1 = wt[1], w2 = wt[2];
    const float w3 = wt[3], w4 = wt[4], w5 = wt[5];
    const float w6 = wt[6], w7 = wt[7], w8 = wt[8];

    // R[0] = col c0-1, R[1..4] = cols c0..c0+3, R[5] = col c0+4
    float T[6], M[6], B[6];

    {
        int ry = y - 1;
        if (ry < 0) {
            T[0]=T[1]=T[2]=T[3]=T[4]=T[5]=0.f;
        } else {
            const float* p = img + (size_t)ry * IMG_W + c0;
            float4 v = *(const float4*)p;
            T[1]=v.x; T[2]=v.y; T[3]=v.z; T[4]=v.w;
            T[0] = (c0 > 0)           ? p[-1] : 0.f;
            T[5] = (c0 + 4 < IMG_W)   ? p[4]  : 0.f;
        }
    }
    {
        const float* p = img + (size_t)y * IMG_W + c0;
        float4 v = *(const float4*)p;
        M[1]=v.x; M[2]=v.y; M[3]=v.z; M[4]=v.w;
        M[0] = (c0 > 0)           ? p[-1] : 0.f;
        M[5] = (c0 + 4 < IMG_W)   ? p[4]  : 0.f;
    }
    {
        int ry = y + 1;
        if (ry >= IMG_H) {
            B[0]=B[1]=B[2]=B[3]=B[4]=B[5]=0.f;
        } else {
            const float* p = img + (size_t)ry * IMG_W + c0;
            float4 v = *(const float4*)p;
            B[1]=v.x; B[2]=v.y; B[3]=v.z; B[4]=v.w;
            B[0] = (c0 > 0)           ? p[-1] : 0.f;
            B[5] = (c0 + 4 < IMG_W)   ? p[4]  : 0.f;
        }
    }

    float4 r;
    float* rp = &r.x;
#pragma unroll
    for (int j = 0; j < 4; ++j) {
        rp[j] = w0*T[j] + w1*T[j+1] + w2*T[j+2]
              + w3*M[j] + w4*M[j+1] + w5*M[j+2]
              + w6*B[j] + w7*B[j+1] + w8*B[j+2];
    }

    *(float4*)orow = r;
}

extern "C" void kernel_launch(void* const* d_in, const int* in_sizes, int n_in,
                              void* d_out, int out_size, void* d_ws, size_t ws_size,
                              hipStream_t stream) {
    const float* X  = (const float*)d_in[0];
    const float* wt = (const float*)d_in[1];
    float* out = (float*)d_out;

    dim3 grid(IMG_H, BATCH);   // one block per (row, batch)
    dim3 block(256);           // 256 threads * 4 cols = 1024 cols
    conv3x3_kernel<<<grid, block, 0, stream>>>(X, wt, out);
}

// Round 3
// 229.575 us; speedup vs baseline: 1.0751x; 1.0751x over previous
//
#include <hip/hip_runtime.h>

#define IMG_W 1024
#define IMG_H 1024
#define BATCH 32
#define ROWS 8   // output rows per thread

typedef float vfloat4 __attribute__((ext_vector_type(4)));

__global__ __launch_bounds__(256) void conv3x3_kernel(
    const float* __restrict__ X,
    const float* __restrict__ wt,
    float* __restrict__ out)
{
    const int y0 = blockIdx.x * ROWS;      // first output row of this block
    const int b  = blockIdx.y;             // batch
    const int c0 = threadIdx.x * 4;        // first of 4 output cols

    const float* img = X + (size_t)b * IMG_H * IMG_W;

    const float w0 = wt[0], w1 = wt[1], w2 = wt[2];
    const float w3 = wt[3], w4 = wt[4], w5 = wt[5];
    const float w6 = wt[6], w7 = wt[7], w8 = wt[8];

    // R[i] holds input row y0-1+i, cols c0-1 .. c0+4
    float R[ROWS + 2][6];

#pragma unroll
    for (int i = 0; i < ROWS + 2; ++i) {
        const int ry = y0 + i - 1;
        if (ry >= 0 && ry < IMG_H) {
            const float* p = img + (size_t)ry * IMG_W + c0;
            const vfloat4 v = *(const vfloat4*)p;
            R[i][1] = v.x; R[i][2] = v.y; R[i][3] = v.z; R[i][4] = v.w;
            R[i][0] = (c0 > 0)         ? p[-1] : 0.f;
            R[i][5] = (c0 + 4 < IMG_W) ? p[4]  : 0.f;
        } else {
            R[i][0] = R[i][1] = R[i][2] = R[i][3] = R[i][4] = R[i][5] = 0.f;
        }
    }

    float* obase = out + ((size_t)b * IMG_H + y0) * IMG_W + c0;

#pragma unroll
    for (int i = 0; i < ROWS; ++i) {
        vfloat4 r;
#pragma unroll
        for (int j = 0; j < 4; ++j) {
            r[j] = w0 * R[i][j]     + w1 * R[i][j + 1]     + w2 * R[i][j + 2]
                 + w3 * R[i + 1][j] + w4 * R[i + 1][j + 1] + w5 * R[i + 1][j + 2]
                 + w6 * R[i + 2][j] + w7 * R[i + 2][j + 1] + w8 * R[i + 2][j + 2];
        }
        // nontemporal: don't let the write stream evict reusable input rows in L2
        __builtin_nontemporal_store(r, (vfloat4*)(obase + (size_t)i * IMG_W));
    }
}

extern "C" void kernel_launch(void* const* d_in, const int* in_sizes, int n_in,
                              void* d_out, int out_size, void* d_ws, size_t ws_size,
                              hipStream_t stream) {
    const float* X  = (const float*)d_in[0];
    const float* wt = (const float*)d_in[1];
    float* out = (float*)d_out;

    dim3 grid(IMG_H / ROWS, BATCH);   // 128 x 32 = 4096 blocks
    dim3 block(256);                  // 256 threads * 4 cols = 1024 cols
    conv3x3_kernel<<<grid, block, 0, stream>>>(X, wt, out);
}